// Round 2
// baseline (8500.787 us; speedup 1.0000x reference)
//
#include <hip/hip_runtime.h>
#include <hip/hip_bf16.h>

// ---------------------------------------------------------------------------
// StateSpaceLite: u = x@W_in^T + b_in  (bf16 MFMA GEMM, fp32 out, in d_out)
// then per-b sequential scan (64 independent blocks, no grid sync):
//   driven = tanh(u_t + state@W_state^T + b_state)
//   state  = d*state + (1-d)*driven ; y = LN(state)*gamma + beta
// W_state streamed as packed bf16 (2 MB, L2-resident), state in LDS.
// ---------------------------------------------------------------------------

typedef __attribute__((ext_vector_type(8))) __bf16 bf16x8;
typedef __attribute__((ext_vector_type(4))) float f32x4;

static __device__ __forceinline__ unsigned f2bf_bits(float f) {
    unsigned u = __float_as_uint(f);
    unsigned r = u + 0x7FFFu + ((u >> 16) & 1u);   // RNE (inputs are finite)
    return r >> 16;
}
static __device__ __forceinline__ float blo(unsigned v) { return __uint_as_float(v << 16); }
static __device__ __forceinline__ float bhi(unsigned v) { return __uint_as_float(v & 0xFFFF0000u); }

// --------------------------- W_state pack kernel ---------------------------
// out[(k/8)*1024 + h] = uint4 of 8 bf16 = W_state[h][k..k+7]
__global__ __launch_bounds__(128)
void pack_wstate(const float* __restrict__ W, uint4* __restrict__ out) {
    const int h = blockIdx.x;      // 0..1023
    const int t = threadIdx.x;     // 0..127 -> k0 = t*8
    const float* src = W + (size_t)h * 1024 + t * 8;
    unsigned us[8];
#pragma unroll
    for (int j = 0; j < 8; ++j) us[j] = f2bf_bits(src[j]);
    uint4 v;
    v.x = us[0] | (us[1] << 16);
    v.y = us[2] | (us[3] << 16);
    v.z = us[4] | (us[5] << 16);
    v.w = us[6] | (us[7] << 16);
    out[(size_t)t * 1024 + h] = v;
}

// ------------------------------- u GEMM ------------------------------------
// C[m][n] = sum_k X[m][k] * Win[n][k] + bin[n]; M=32768 N=1024 K=512
#define BM 128
#define BN 128
#define BKK 32
#define LDT 40   // padded LDS stride (elements); 40*2B=80B keeps 16B alignment

__global__ __launch_bounds__(256)
void u_gemm(const float* __restrict__ X, const float* __restrict__ Win,
            const float* __restrict__ bin, float* __restrict__ U) {
    __shared__ unsigned short Al[BM][LDT];
    __shared__ unsigned short Bl[BN][LDT];
    const int tid = threadIdx.x;
    const int m0 = blockIdx.y * BM;
    const int n0 = blockIdx.x * BN;
    const int l  = tid & 63;
    const int w  = tid >> 6;
    const int wr = (w >> 1) * 64, wc = (w & 1) * 64;
    const int fr = l & 15, fk = (l >> 4) * 8;

    f32x4 acc[4][4];
#pragma unroll
    for (int m = 0; m < 4; ++m)
#pragma unroll
        for (int n = 0; n < 4; ++n) acc[m][n] = f32x4{0.f, 0.f, 0.f, 0.f};

    const int sr = tid >> 1;          // 0..127: staged row
    const int sc = (tid & 1) * 16;    // k-offset 0 or 16

    for (int k0 = 0; k0 < 512; k0 += BKK) {
        const float* ap = X   + (size_t)(m0 + sr) * 512 + k0 + sc;
        const float* bp = Win + (size_t)(n0 + sr) * 512 + k0 + sc;
        float a[16], b[16];
#pragma unroll
        for (int j = 0; j < 4; ++j) {
            *(float4*)&a[j * 4] = *(const float4*)(ap + j * 4);
            *(float4*)&b[j * 4] = *(const float4*)(bp + j * 4);
        }
        __syncthreads();   // previous iteration's frag reads complete
#pragma unroll
        for (int j = 0; j < 16; ++j) {
            Al[sr][sc + j] = (unsigned short)f2bf_bits(a[j]);
            Bl[sr][sc + j] = (unsigned short)f2bf_bits(b[j]);
        }
        __syncthreads();

        bf16x8 af[4], bf[4];
#pragma unroll
        for (int m = 0; m < 4; ++m)
            af[m] = *(const bf16x8*)&Al[wr + m * 16 + fr][fk];
#pragma unroll
        for (int n = 0; n < 4; ++n)
            bf[n] = *(const bf16x8*)&Bl[wc + n * 16 + fr][fk];
#pragma unroll
        for (int m = 0; m < 4; ++m)
#pragma unroll
            for (int n = 0; n < 4; ++n)
                acc[m][n] = __builtin_amdgcn_mfma_f32_16x16x32_bf16(
                    af[m], bf[n], acc[m][n], 0, 0, 0);
    }

#pragma unroll
    for (int m = 0; m < 4; ++m) {
#pragma unroll
        for (int n = 0; n < 4; ++n) {
            const int col = n0 + wc + n * 16 + fr;
            const float bb = bin[col];
#pragma unroll
            for (int r = 0; r < 4; ++r) {
                const int row = m0 + wr + m * 16 + (l >> 4) * 4 + r;
                U[(size_t)row * 1024 + col] = acc[m][n][r] + bb;
            }
        }
    }
}

// ----------------------------- recurrence ----------------------------------
// One block per batch element b; 1024 threads, thread h owns output channel h.
// u (input) and y (output) share the same buffer: u[b,t,h] is consumed by the
// only thread that writes y[b,t,h].
__global__ __launch_bounds__(1024)
void rec_step_all(const uint4* __restrict__ Wp, float* __restrict__ UY,
                  const float* __restrict__ b_state, const float* __restrict__ decay,
                  const float* __restrict__ gamma, const float* __restrict__ beta) {
    __shared__ __align__(16) float st[1024];
    __shared__ float red1[16], red2[16];
    const int b = blockIdx.x;
    const int h = threadIdx.x;
    const float bs = b_state[h];
    const float g  = gamma[h], be = beta[h];
    const float dd = 1.f / (1.f + __expf(-decay[h]));
    float sh = 0.f;
    st[h] = 0.f;
    float* row = UY + (size_t)b * 512 * 1024;
    __syncthreads();

    for (int t = 0; t < 512; ++t) {
        float acc = row[t * 1024 + h] + bs;
        const uint4* wp = Wp + h;
#pragma unroll 8
        for (int kk = 0; kk < 128; ++kk) {
            const uint4 w4 = wp[(size_t)kk * 1024];
            const float4 s0 = *(const float4*)&st[kk * 8];
            const float4 s1 = *(const float4*)&st[kk * 8 + 4];
            acc = fmaf(blo(w4.x), s0.x, acc);
            acc = fmaf(bhi(w4.x), s0.y, acc);
            acc = fmaf(blo(w4.y), s0.z, acc);
            acc = fmaf(bhi(w4.y), s0.w, acc);
            acc = fmaf(blo(w4.z), s1.x, acc);
            acc = fmaf(bhi(w4.z), s1.y, acc);
            acc = fmaf(blo(w4.w), s1.z, acc);
            acc = fmaf(bhi(w4.w), s1.w, acc);
        }
        const float driven = tanhf(acc);
        const float ns = dd * sh + (1.f - dd) * driven;
        sh = ns;
        __syncthreads();            // all k-loop reads of st done
        st[h] = ns;

        float v1 = ns, v2 = ns * ns;
#pragma unroll
        for (int o = 32; o > 0; o >>= 1) {
            v1 += __shfl_down(v1, o);
            v2 += __shfl_down(v2, o);
        }
        if ((h & 63) == 0) { red1[h >> 6] = v1; red2[h >> 6] = v2; }
        __syncthreads();            // st + partial sums visible

        float S1 = 0.f, S2 = 0.f;
#pragma unroll
        for (int i = 0; i < 16; ++i) { S1 += red1[i]; S2 += red2[i]; }
        const float mu  = S1 * (1.f / 1024.f);
        const float var = S2 * (1.f / 1024.f) - mu * mu;
        const float rs  = rsqrtf(var + 1e-5f);
        row[t * 1024 + h] = (ns - mu) * rs * g + be;
    }
}

// ---------------------------------------------------------------------------
extern "C" void kernel_launch(void* const* d_in, const int* in_sizes, int n_in,
                              void* d_out, int out_size, void* d_ws, size_t ws_size,
                              hipStream_t stream) {
    const float* x    = (const float*)d_in[0];
    const float* Win  = (const float*)d_in[1];
    const float* bin  = (const float*)d_in[2];
    const float* Wst  = (const float*)d_in[3];
    const float* bst  = (const float*)d_in[4];
    const float* dec  = (const float*)d_in[5];
    const float* lng  = (const float*)d_in[6];
    const float* lnb  = (const float*)d_in[7];
    float* out = (float*)d_out;
    uint4* Wp  = (uint4*)d_ws;                    // 2 MB packed bf16 W_state

    pack_wstate<<<1024, 128, 0, stream>>>(Wst, Wp);
    u_gemm<<<dim3(8, 256), 256, 0, stream>>>(x, Win, bin, out);
    rec_step_all<<<64, 1024, 0, stream>>>(Wp, out, bst, dec, lng, lnb);
}

// Round 3
// 7048.046 us; speedup vs baseline: 1.2061x; 1.2061x over previous
//
#include <hip/hip_runtime.h>
#include <hip/hip_bf16.h>

// ---------------------------------------------------------------------------
// StateSpaceLite on MI355X.
//   u = x@W_in^T + b_in            (bf16 MFMA GEMM -> d_out, in place)
//   scan over t: driven = tanh(u_t + s@W_state^T + b_state)
//                s' = d*s + (1-d)*driven ; y_t = LN(s')*gamma + beta
// Round-3 structure: 64 blocks = 64 column-slices (16 cols each), each block
// handles ALL 64 batch rows with MFMA. W slice lives in LDS (loaded once).
// State exchanged as bf16 [64][1024] in d_ws, double buffered, one custom
// device-scope barrier per step (64 co-resident blocks). Own-column state
// kept in fp32 registers for exact recurrence feedback.
// ---------------------------------------------------------------------------

#define B_    64
#define T_    512
#define D_    512
#define H_    1024
#define NBLK  64
#define COLS  16
#define KSTEPS 32   // H_/32

typedef __attribute__((ext_vector_type(8))) __bf16 bf16x8;
typedef __attribute__((ext_vector_type(4))) float f32x4;

static __device__ __forceinline__ unsigned f2bf_bits(float f) {
    unsigned u = __float_as_uint(f);
    return (u + 0x7FFFu + ((u >> 16) & 1u)) >> 16;   // RNE, finite inputs
}
static __device__ __forceinline__ float blo(unsigned v) { return __uint_as_float(v << 16); }
static __device__ __forceinline__ float bhi(unsigned v) { return __uint_as_float(v & 0xFFFF0000u); }

static __device__ __forceinline__ float fast_tanh(float x) {
    x = fminf(fmaxf(x, -15.f), 15.f);
    const float e = __expf(2.f * x);                  // finite after clamp
    return 1.f - 2.f * __builtin_amdgcn_rcpf(e + 1.f);
}

// ------------------------------- u GEMM ------------------------------------
// C[m][n] = sum_k X[m][k]*Win[n][k] + bin[n]; M=32768 N=1024 K=512 (verified)
#define BM 128
#define BN 128
#define BKK 32
#define LDT 40

__global__ __launch_bounds__(256)
void u_gemm(const float* __restrict__ X, const float* __restrict__ Win,
            const float* __restrict__ bin, float* __restrict__ U) {
    __shared__ unsigned short Al[BM][LDT];
    __shared__ unsigned short Bl[BN][LDT];
    const int tid = threadIdx.x;
    const int m0 = blockIdx.y * BM;
    const int n0 = blockIdx.x * BN;
    const int l  = tid & 63;
    const int w  = tid >> 6;
    const int wr = (w >> 1) * 64, wc = (w & 1) * 64;
    const int fr = l & 15, fk = (l >> 4) * 8;

    f32x4 acc[4][4];
#pragma unroll
    for (int m = 0; m < 4; ++m)
#pragma unroll
        for (int n = 0; n < 4; ++n) acc[m][n] = f32x4{0.f, 0.f, 0.f, 0.f};

    const int sr = tid >> 1;
    const int sc = (tid & 1) * 16;

    for (int k0 = 0; k0 < 512; k0 += BKK) {
        const float* ap = X   + (size_t)(m0 + sr) * 512 + k0 + sc;
        const float* bp = Win + (size_t)(n0 + sr) * 512 + k0 + sc;
        float a[16], b[16];
#pragma unroll
        for (int j = 0; j < 4; ++j) {
            *(float4*)&a[j * 4] = *(const float4*)(ap + j * 4);
            *(float4*)&b[j * 4] = *(const float4*)(bp + j * 4);
        }
        __syncthreads();
#pragma unroll
        for (int j = 0; j < 16; ++j) {
            Al[sr][sc + j] = (unsigned short)f2bf_bits(a[j]);
            Bl[sr][sc + j] = (unsigned short)f2bf_bits(b[j]);
        }
        __syncthreads();

        bf16x8 af[4], bf[4];
#pragma unroll
        for (int m = 0; m < 4; ++m)
            af[m] = *(const bf16x8*)&Al[wr + m * 16 + fr][fk];
#pragma unroll
        for (int n = 0; n < 4; ++n)
            bf[n] = *(const bf16x8*)&Bl[wc + n * 16 + fr][fk];
#pragma unroll
        for (int m = 0; m < 4; ++m)
#pragma unroll
            for (int n = 0; n < 4; ++n)
                acc[m][n] = __builtin_amdgcn_mfma_f32_16x16x32_bf16(
                    af[m], bf[n], acc[m][n], 0, 0, 0);
    }

#pragma unroll
    for (int m = 0; m < 4; ++m) {
#pragma unroll
        for (int n = 0; n < 4; ++n) {
            const int col = n0 + wc + n * 16 + fr;
            const float bb = bin[col];
#pragma unroll
            for (int r = 0; r < 4; ++r) {
                const int row = m0 + wr + m * 16 + (l >> 4) * 4 + r;
                U[(size_t)row * 1024 + col] = acc[m][n][r] + bb;
            }
        }
    }
}

// ----------------------------- recurrence ----------------------------------
__global__ __launch_bounds__(256, 1)
void rec_mfma(const float* __restrict__ Wst, float* __restrict__ UY,
              const float* __restrict__ b_state, const float* __restrict__ decay,
              const float* __restrict__ gamma, const float* __restrict__ beta,
              unsigned short* __restrict__ S0, unsigned short* __restrict__ S1,
              unsigned* __restrict__ ctr) {
    __shared__ __align__(16) unsigned short Wl[128][COLS][8];  // [k/8][col][8] bf16
    __shared__ float mu_s[64], rs_s[64];

    const int tid  = threadIdx.x;
    const int bid  = blockIdx.x;
    const int h0   = bid * COLS;
    const int wave = tid >> 6;          // 0..3 -> b-tile
    const int lane = tid & 63;
    const int c    = lane & 15;         // local col (B-frag col, C/D col)
    const int rgrp = lane >> 4;         // 0..3
    const int arow = lane & 15;         // A-frag row within 16-row tile

    // ---- W slice -> LDS (bf16), loaded exactly once ----
    {
        const int col = tid >> 4;       // 0..15
        const int sub = tid & 15;       // kc = sub*8+i
        const float* wr_ = Wst + (size_t)(h0 + col) * H_ + sub * 64;
#pragma unroll
        for (int i = 0; i < 8; ++i) {
            float4 f0 = *(const float4*)(wr_ + i * 8);
            float4 f1 = *(const float4*)(wr_ + i * 8 + 4);
            unsigned short* dst = &Wl[sub * 8 + i][col][0];
            dst[0] = (unsigned short)f2bf_bits(f0.x);
            dst[1] = (unsigned short)f2bf_bits(f0.y);
            dst[2] = (unsigned short)f2bf_bits(f0.z);
            dst[3] = (unsigned short)f2bf_bits(f0.w);
            dst[4] = (unsigned short)f2bf_bits(f1.x);
            dst[5] = (unsigned short)f2bf_bits(f1.y);
            dst[6] = (unsigned short)f2bf_bits(f1.z);
            dst[7] = (unsigned short)f2bf_bits(f1.w);
        }
    }

    const float d_c  = 1.f / (1.f + __expf(-decay[h0 + c]));
    const float od_c = 1.f - d_c;
    const float bs_c = b_state[h0 + c];
    const float g_c  = gamma[h0 + c];
    const float be_c = beta[h0 + c];

    float sold[4] = {0.f, 0.f, 0.f, 0.f};   // own fp32 state: rows brow[r], col h0+c
    int brow[4];
#pragma unroll
    for (int r = 0; r < 4; ++r) brow[r] = wave * 16 + rgrp * 4 + r;

    __syncthreads();

    for (int t = 0; t < T_; ++t) {
        const unsigned short* Sr = (t & 1) ? S1 : S0;
        unsigned short*       Sw = (t & 1) ? S0 : S1;

        // u loads issued early; consumed in the epilogue only
        float uu[4];
#pragma unroll
        for (int r = 0; r < 4; ++r)
            uu[r] = UY[((size_t)brow[r] * T_ + t) * H_ + h0 + c];

        f32x4 acc = {0.f, 0.f, 0.f, 0.f};
        float s1 = 0.f, s2 = 0.f;
        const unsigned short* sr_base =
            Sr + (size_t)(wave * 16 + arow) * H_ + rgrp * 8;

#pragma unroll 8
        for (int kk = 0; kk < KSTEPS; ++kk) {
            const uint4 aw = *(const uint4*)(sr_base + kk * 32);
            const bf16x8 af = __builtin_bit_cast(bf16x8, aw);
            const bf16x8 bf = *(const bf16x8*)(&Wl[kk * 4 + rgrp][c][0]);
            acc = __builtin_amdgcn_mfma_f32_16x16x32_bf16(af, bf, acc, 0, 0, 0);
            // LN stats of s_t from the same 16B
            const float e0 = blo(aw.x), e1 = bhi(aw.x), e2 = blo(aw.y), e3 = bhi(aw.y);
            const float e4 = blo(aw.z), e5 = bhi(aw.z), e6 = blo(aw.w), e7 = bhi(aw.w);
            s1 += ((e0 + e1) + (e2 + e3)) + ((e4 + e5) + (e6 + e7));
            s2 = fmaf(e0, e0, s2); s2 = fmaf(e1, e1, s2);
            s2 = fmaf(e2, e2, s2); s2 = fmaf(e3, e3, s2);
            s2 = fmaf(e4, e4, s2); s2 = fmaf(e5, e5, s2);
            s2 = fmaf(e6, e6, s2); s2 = fmaf(e7, e7, s2);
        }

        // reduce stats over the 4 k-groups (lanes 16 apart share a b-row)
        s1 += __shfl_xor(s1, 16); s1 += __shfl_xor(s1, 32);
        s2 += __shfl_xor(s2, 16); s2 += __shfl_xor(s2, 32);
        if (lane < 16) {
            const float mu  = s1 * (1.f / (float)H_);
            const float var = s2 * (1.f / (float)H_) - mu * mu;
            mu_s[wave * 16 + lane] = mu;
            rs_s[wave * 16 + lane] = rsqrtf(var + 1e-5f);
        }
        __syncthreads();

        // y_{t-1} = LN(s_t): own columns are exact fp32 in sold[]
        if (t > 0) {
#pragma unroll
            for (int r = 0; r < 4; ++r)
                UY[((size_t)brow[r] * T_ + (t - 1)) * H_ + h0 + c] =
                    (sold[r] - mu_s[brow[r]]) * rs_s[brow[r]] * g_c + be_c;
        }

        // state update (fp32 feedback), publish bf16 copy
#pragma unroll
        for (int r = 0; r < 4; ++r) {
            const float pre = acc[r] + uu[r] + bs_c;
            const float sn  = d_c * sold[r] + od_c * fast_tanh(pre);
            sold[r] = sn;
            Sw[(size_t)brow[r] * H_ + h0 + c] = (unsigned short)f2bf_bits(sn);
        }

        // ---- device-scope grid barrier (64 co-resident blocks) ----
        __syncthreads();                       // drains all waves' vmem (s_barrier)
        if (tid == 0) {
            __threadfence();                   // release: publish Sw writes
            atomicAdd(ctr, 1u);
            const unsigned tgt = (unsigned)(t + 1) * NBLK;
            while (__hip_atomic_load(ctr, __ATOMIC_RELAXED,
                                     __HIP_MEMORY_SCOPE_AGENT) < tgt)
                __builtin_amdgcn_s_sleep(2);
            __threadfence();                   // acquire: invalidate for S reads
        }
        __syncthreads();
    }

    // ---- final LN pass: y_{511} = LN(s_512), s_512 lives in S0 (T_ even) ----
    {
        const unsigned short* Sr = (T_ & 1) ? S1 : S0;
        float s1 = 0.f, s2 = 0.f;
        const unsigned short* sr_base =
            Sr + (size_t)(wave * 16 + arow) * H_ + rgrp * 8;
#pragma unroll 8
        for (int kk = 0; kk < KSTEPS; ++kk) {
            const uint4 aw = *(const uint4*)(sr_base + kk * 32);
            const float e0 = blo(aw.x), e1 = bhi(aw.x), e2 = blo(aw.y), e3 = bhi(aw.y);
            const float e4 = blo(aw.z), e5 = bhi(aw.z), e6 = blo(aw.w), e7 = bhi(aw.w);
            s1 += ((e0 + e1) + (e2 + e3)) + ((e4 + e5) + (e6 + e7));
            s2 = fmaf(e0, e0, s2); s2 = fmaf(e1, e1, s2);
            s2 = fmaf(e2, e2, s2); s2 = fmaf(e3, e3, s2);
            s2 = fmaf(e4, e4, s2); s2 = fmaf(e5, e5, s2);
            s2 = fmaf(e6, e6, s2); s2 = fmaf(e7, e7, s2);
        }
        s1 += __shfl_xor(s1, 16); s1 += __shfl_xor(s1, 32);
        s2 += __shfl_xor(s2, 16); s2 += __shfl_xor(s2, 32);
        if (lane < 16) {
            const float mu  = s1 * (1.f / (float)H_);
            const float var = s2 * (1.f / (float)H_) - mu * mu;
            mu_s[wave * 16 + lane] = mu;
            rs_s[wave * 16 + lane] = rsqrtf(var + 1e-5f);
        }
        __syncthreads();
#pragma unroll
        for (int r = 0; r < 4; ++r)
            UY[((size_t)brow[r] * T_ + (T_ - 1)) * H_ + h0 + c] =
                (sold[r] - mu_s[brow[r]]) * rs_s[brow[r]] * g_c + be_c;
    }
}

// ---------------------------------------------------------------------------
extern "C" void kernel_launch(void* const* d_in, const int* in_sizes, int n_in,
                              void* d_out, int out_size, void* d_ws, size_t ws_size,
                              hipStream_t stream) {
    const float* x   = (const float*)d_in[0];
    const float* Win = (const float*)d_in[1];
    const float* bin = (const float*)d_in[2];
    const float* Wst = (const float*)d_in[3];
    const float* bst = (const float*)d_in[4];
    const float* dec = (const float*)d_in[5];
    const float* lng = (const float*)d_in[6];
    const float* lnb = (const float*)d_in[7];
    float* out = (float*)d_out;

    unsigned char* ws = (unsigned char*)d_ws;
    unsigned*       ctr = (unsigned*)ws;                         // 4 B (zeroed)
    unsigned short* S0  = (unsigned short*)(ws + 256);           // 128 KB
    unsigned short* S1  = (unsigned short*)(ws + 256 + B_ * H_ * 2);

    hipMemsetAsync(d_ws, 0, 256 + 2 * B_ * H_ * 2, stream);      // ctr=0, s_0=0
    u_gemm<<<dim3(8, 256), 256, 0, stream>>>(x, Win, bin, out);
    rec_mfma<<<NBLK, 256, 0, stream>>>(Wst, out, bst, dec, lng, lnb, S0, S1, ctr);
}

// Round 5
// 4560.670 us; speedup vs baseline: 1.8639x; 1.5454x over previous
//
#include <hip/hip_runtime.h>
#include <hip/hip_bf16.h>

// ---------------------------------------------------------------------------
// StateSpaceLite on MI355X.
//   u = x@W_in^T + b_in            (bf16 MFMA GEMM -> d_out, in place)
//   scan over t: driven = tanh(u_t + s@W_state^T + b_state)
//                s' = d*s + (1-d)*driven ; y_t = LN(s')*gamma + beta
// Round-4: 64 blocks = 64 column-slices (16 cols), all 64 batch rows via MFMA.
// W slice in LDS. Cross-block exchange: bf16 state + fp32 LN partials written
// with agent-scope relaxed atomic stores (write-through to IC, no L2 dirty),
// per-block flag barrier (no atomicAdd contention), ONE acquire fence
// (single buffer_inv) per block per step; all shared reads are plain
// vectorized loads (pipelined dwordx4). No buffer_wbl2 anywhere.
// ---------------------------------------------------------------------------

#define B_    64
#define T_    512
#define H_    1024
#define NBLK  64
#define COLS  16
#define KSTEPS 32   // H_/32

typedef __attribute__((ext_vector_type(8))) __bf16 bf16x8;
typedef __attribute__((ext_vector_type(4))) float f32x4;

static __device__ __forceinline__ unsigned f2bf_bits(float f) {
    unsigned u = __float_as_uint(f);
    return (u + 0x7FFFu + ((u >> 16) & 1u)) >> 16;   // RNE, finite inputs
}

static __device__ __forceinline__ float fast_tanh(float x) {
    x = fminf(fmaxf(x, -15.f), 15.f);
    const float e = __expf(2.f * x);                  // finite after clamp
    return 1.f - 2.f * __builtin_amdgcn_rcpf(e + 1.f);
}

// ------------------------------- u GEMM ------------------------------------
// C[m][n] = sum_k X[m][k]*Win[n][k] + bin[n]; M=32768 N=1024 K=512 (verified)
#define BM 128
#define BN 128
#define BKK 32
#define LDT 40

__global__ __launch_bounds__(256)
void u_gemm(const float* __restrict__ X, const float* __restrict__ Win,
            const float* __restrict__ bin, float* __restrict__ U) {
    __shared__ unsigned short Al[BM][LDT];
    __shared__ unsigned short Bl[BN][LDT];
    const int tid = threadIdx.x;
    const int m0 = blockIdx.y * BM;
    const int n0 = blockIdx.x * BN;
    const int l  = tid & 63;
    const int w  = tid >> 6;
    const int wr = (w >> 1) * 64, wc = (w & 1) * 64;
    const int fr = l & 15, fk = (l >> 4) * 8;

    f32x4 acc[4][4];
#pragma unroll
    for (int m = 0; m < 4; ++m)
#pragma unroll
        for (int n = 0; n < 4; ++n) acc[m][n] = f32x4{0.f, 0.f, 0.f, 0.f};

    const int sr = tid >> 1;
    const int sc = (tid & 1) * 16;

    for (int k0 = 0; k0 < 512; k0 += BKK) {
        const float* ap = X   + (size_t)(m0 + sr) * 512 + k0 + sc;
        const float* bp = Win + (size_t)(n0 + sr) * 512 + k0 + sc;
        float a[16], b[16];
#pragma unroll
        for (int j = 0; j < 4; ++j) {
            *(float4*)&a[j * 4] = *(const float4*)(ap + j * 4);
            *(float4*)&b[j * 4] = *(const float4*)(bp + j * 4);
        }
        __syncthreads();
#pragma unroll
        for (int j = 0; j < 16; ++j) {
            Al[sr][sc + j] = (unsigned short)f2bf_bits(a[j]);
            Bl[sr][sc + j] = (unsigned short)f2bf_bits(b[j]);
        }
        __syncthreads();

        bf16x8 af[4], bf[4];
#pragma unroll
        for (int m = 0; m < 4; ++m)
            af[m] = *(const bf16x8*)&Al[wr + m * 16 + fr][fk];
#pragma unroll
        for (int n = 0; n < 4; ++n)
            bf[n] = *(const bf16x8*)&Bl[wc + n * 16 + fr][fk];
#pragma unroll
        for (int m = 0; m < 4; ++m)
#pragma unroll
            for (int n = 0; n < 4; ++n)
                acc[m][n] = __builtin_amdgcn_mfma_f32_16x16x32_bf16(
                    af[m], bf[n], acc[m][n], 0, 0, 0);
    }

#pragma unroll
    for (int m = 0; m < 4; ++m) {
#pragma unroll
        for (int n = 0; n < 4; ++n) {
            const int col = n0 + wc + n * 16 + fr;
            const float bb = bin[col];
#pragma unroll
            for (int r = 0; r < 4; ++r) {
                const int row = m0 + wr + m * 16 + (l >> 4) * 4 + r;
                U[(size_t)row * 1024 + col] = acc[m][n][r] + bb;
            }
        }
    }
}

// ----------------------------- recurrence ----------------------------------
__global__ __launch_bounds__(256, 1)
void rec_mfma(const float* __restrict__ Wst, float* __restrict__ UY,
              const float* __restrict__ b_state, const float* __restrict__ decay,
              const float* __restrict__ gamma, const float* __restrict__ beta,
              unsigned short* __restrict__ S0, unsigned short* __restrict__ S1,
              float2* __restrict__ P0, float2* __restrict__ P1,
              unsigned* __restrict__ flags) {
    __shared__ __align__(16) unsigned short Wl[128][COLS][8];  // [k/8][col][8] bf16
    __shared__ float mu_s[64], rs_s[64];

    const int tid  = threadIdx.x;
    const int bid  = blockIdx.x;
    const int h0   = bid * COLS;
    const int wave = tid >> 6;          // 0..3 -> b-tile
    const int lane = tid & 63;
    const int c    = lane & 15;         // local col = A-frag row = C/D col
    const int rgrp = lane >> 4;         // 0..3 (k-chunk / C/D row group)

    // ---- W slice -> LDS (bf16), loaded exactly once ----
    {
        const int col = tid >> 4;       // 0..15
        const int sub = tid & 15;
        const float* wr_ = Wst + (size_t)(h0 + col) * H_ + sub * 64;
#pragma unroll
        for (int i = 0; i < 8; ++i) {
            float4 f0 = *(const float4*)(wr_ + i * 8);
            float4 f1 = *(const float4*)(wr_ + i * 8 + 4);
            unsigned short* dst = &Wl[sub * 8 + i][col][0];
            dst[0] = (unsigned short)f2bf_bits(f0.x);
            dst[1] = (unsigned short)f2bf_bits(f0.y);
            dst[2] = (unsigned short)f2bf_bits(f0.z);
            dst[3] = (unsigned short)f2bf_bits(f0.w);
            dst[4] = (unsigned short)f2bf_bits(f1.x);
            dst[5] = (unsigned short)f2bf_bits(f1.y);
            dst[6] = (unsigned short)f2bf_bits(f1.z);
            dst[7] = (unsigned short)f2bf_bits(f1.w);
        }
    }

    const float d_c  = 1.f / (1.f + __expf(-decay[h0 + c]));
    const float od_c = 1.f - d_c;
    const float bs_c = b_state[h0 + c];
    const float g_c  = gamma[h0 + c];
    const float be_c = beta[h0 + c];

    float sold[4] = {0.f, 0.f, 0.f, 0.f};
    int brow[4];
#pragma unroll
    for (int r = 0; r < 4; ++r) brow[r] = wave * 16 + rgrp * 4 + r;

    // prefetch u for t=0
    float uu[4];
#pragma unroll
    for (int r = 0; r < 4; ++r)
        uu[r] = UY[(size_t)brow[r] * T_ * H_ + h0 + c];

    __syncthreads();

    for (int t = 0; t < T_; ++t) {
        const unsigned short* Sr = (t & 1) ? S1 : S0;
        unsigned short*       Sw = (t & 1) ? S0 : S1;
        float2*               Pw = (t & 1) ? P1 : P0;

        // ---- phase 1: MFMA  acc = s_t @ Wslice^T (plain pipelined loads) ----
        f32x4 a0 = {0.f,0.f,0.f,0.f}, a1 = a0, a2 = a0, a3 = a0;
        const unsigned short* sr_base = Sr + (size_t)(wave * 16 + c) * H_ + rgrp * 8;
#pragma unroll 8
        for (int kk = 0; kk < KSTEPS; kk += 4) {
            const uint4 w0 = *(const uint4*)(sr_base + (kk + 0) * 32);
            const uint4 w1 = *(const uint4*)(sr_base + (kk + 1) * 32);
            const uint4 w2 = *(const uint4*)(sr_base + (kk + 2) * 32);
            const uint4 w3 = *(const uint4*)(sr_base + (kk + 3) * 32);
            a0 = __builtin_amdgcn_mfma_f32_16x16x32_bf16(
                __builtin_bit_cast(bf16x8, w0),
                *(const bf16x8*)(&Wl[(kk + 0) * 4 + rgrp][c][0]), a0, 0, 0, 0);
            a1 = __builtin_amdgcn_mfma_f32_16x16x32_bf16(
                __builtin_bit_cast(bf16x8, w1),
                *(const bf16x8*)(&Wl[(kk + 1) * 4 + rgrp][c][0]), a1, 0, 0, 0);
            a2 = __builtin_amdgcn_mfma_f32_16x16x32_bf16(
                __builtin_bit_cast(bf16x8, w2),
                *(const bf16x8*)(&Wl[(kk + 2) * 4 + rgrp][c][0]), a2, 0, 0, 0);
            a3 = __builtin_amdgcn_mfma_f32_16x16x32_bf16(
                __builtin_bit_cast(bf16x8, w3),
                *(const bf16x8*)(&Wl[(kk + 3) * 4 + rgrp][c][0]), a3, 0, 0, 0);
        }
        const f32x4 acc = (a0 + a1) + (a2 + a3);

        // ---- phase 2: finish stats of s_t (partials published at t-1), y_{t-1}
        if (t > 0) {
            const float2* Pr = ((t - 1) & 1) ? P1 : P0;
            const int row = tid >> 2, j = tid & 3;
            float s1 = 0.f, s2 = 0.f;
            const float2* pp = Pr + row * NBLK + j * 16;
#pragma unroll
            for (int k = 0; k < 16; k += 2) {
                const float4 v = *(const float4*)(pp + k);
                s1 += v.x + v.z;
                s2 += v.y + v.w;
            }
            s1 += __shfl_xor(s1, 1); s2 += __shfl_xor(s2, 1);
            s1 += __shfl_xor(s1, 2); s2 += __shfl_xor(s2, 2);
            if (j == 0) {
                const float mu  = s1 * (1.f / (float)H_);
                const float var = s2 * (1.f / (float)H_) - mu * mu;
                mu_s[row] = mu;
                rs_s[row] = rsqrtf(var + 1e-5f);
            }
            __syncthreads();
#pragma unroll
            for (int r = 0; r < 4; ++r)
                UY[((size_t)brow[r] * T_ + (t - 1)) * H_ + h0 + c] =
                    (sold[r] - mu_s[brow[r]]) * rs_s[brow[r]] * g_c + be_c;
        }

        // ---- phase 3: state update, publish bf16 state + fp32 partials ----
        float p1v[4], p2v[4];
#pragma unroll
        for (int r = 0; r < 4; ++r) {
            const float pre = acc[r] + uu[r] + bs_c;
            const float sn  = d_c * sold[r] + od_c * fast_tanh(pre);
            sold[r] = sn;
            p1v[r] = sn;
            p2v[r] = sn * sn;
            __hip_atomic_store(&Sw[(size_t)brow[r] * H_ + h0 + c],
                               (unsigned short)f2bf_bits(sn),
                               __ATOMIC_RELAXED, __HIP_MEMORY_SCOPE_AGENT);
        }
#pragma unroll
        for (int o = 1; o < 16; o <<= 1) {
#pragma unroll
            for (int r = 0; r < 4; ++r) {
                p1v[r] += __shfl_xor(p1v[r], o);
                p2v[r] += __shfl_xor(p2v[r], o);
            }
        }
        if (c == 0) {
#pragma unroll
            for (int r = 0; r < 4; ++r) {
                const float2 pv = {p1v[r], p2v[r]};
                __hip_atomic_store((unsigned long long*)&Pw[brow[r] * NBLK + bid],
                                   __builtin_bit_cast(unsigned long long, pv),
                                   __ATOMIC_RELAXED, __HIP_MEMORY_SCOPE_AGENT);
            }
        }

        // ---- phase 4: prefetch u for t+1 (hidden behind barrier wait) ----
        if (t + 1 < T_) {
#pragma unroll
            for (int r = 0; r < 4; ++r)
                uu[r] = UY[((size_t)brow[r] * T_ + (t + 1)) * H_ + h0 + c];
        }

        // ---- phase 5: flag barrier; one acquire (buffer_inv) per block ----
        __syncthreads();   // drains vmcnt per wave: all atomic stores at IC
        if (tid == 0)
            __hip_atomic_store(&flags[bid], (unsigned)(t + 1),
                               __ATOMIC_RELAXED, __HIP_MEMORY_SCOPE_AGENT);
        if (wave == 0) {
            const unsigned tgt = (unsigned)(t + 1);
            for (;;) {
                const unsigned v = __hip_atomic_load(&flags[lane],
                                                     __ATOMIC_RELAXED,
                                                     __HIP_MEMORY_SCOPE_AGENT);
                if (__ballot(v >= tgt) == ~0ull) break;
                __builtin_amdgcn_s_sleep(1);
            }
            __builtin_amdgcn_fence(__ATOMIC_ACQUIRE, "agent");
        }
        __syncthreads();
    }

    // ---- epilogue: y_{T-1} = LN(s_T) from partials published at t=T-1 ----
    {
        const float2* Pr = ((T_ - 1) & 1) ? P1 : P0;
        const int row = tid >> 2, j = tid & 3;
        float s1 = 0.f, s2 = 0.f;
        const float2* pp = Pr + row * NBLK + j * 16;
#pragma unroll
        for (int k = 0; k < 16; k += 2) {
            const float4 v = *(const float4*)(pp + k);
            s1 += v.x + v.z;
            s2 += v.y + v.w;
        }
        s1 += __shfl_xor(s1, 1); s2 += __shfl_xor(s2, 1);
        s1 += __shfl_xor(s1, 2); s2 += __shfl_xor(s2, 2);
        if (j == 0) {
            const float mu  = s1 * (1.f / (float)H_);
            const float var = s2 * (1.f / (float)H_) - mu * mu;
            mu_s[row] = mu;
            rs_s[row] = rsqrtf(var + 1e-5f);
        }
        __syncthreads();
#pragma unroll
        for (int r = 0; r < 4; ++r)
            UY[((size_t)brow[r] * T_ + (T_ - 1)) * H_ + h0 + c] =
                (sold[r] - mu_s[brow[r]]) * rs_s[brow[r]] * g_c + be_c;
    }
}

// ---------------------------------------------------------------------------
extern "C" void kernel_launch(void* const* d_in, const int* in_sizes, int n_in,
                              void* d_out, int out_size, void* d_ws, size_t ws_size,
                              hipStream_t stream) {
    const float* x   = (const float*)d_in[0];
    const float* Win = (const float*)d_in[1];
    const float* bin = (const float*)d_in[2];
    const float* Wst = (const float*)d_in[3];
    const float* bst = (const float*)d_in[4];
    const float* dec = (const float*)d_in[5];
    const float* lng = (const float*)d_in[6];
    const float* lnb = (const float*)d_in[7];
    float* out = (float*)d_out;

    unsigned char* ws = (unsigned char*)d_ws;
    unsigned*       flags = (unsigned*)ws;                         // 256 B
    unsigned short* S0 = (unsigned short*)(ws + 4096);             // 128 KB
    unsigned short* S1 = (unsigned short*)(ws + 4096 + 131072);    // 128 KB
    float2*         P0 = (float2*)(ws + 4096 + 262144);            // 32 KB
    float2*         P1 = (float2*)(ws + 4096 + 262144 + 32768);    // 32 KB

    // zero flags + S0 (initial state); S1/P0/P1 are written before first read
    hipMemsetAsync(d_ws, 0, 4096 + 131072, stream);
    u_gemm<<<dim3(8, 256), 256, 0, stream>>>(x, Win, bin, out);
    rec_mfma<<<NBLK, 256, 0, stream>>>(Wst, out, bst, dec, lng, lnb,
                                       S0, S1, P0, P1, flags);
}

// Round 8
// 4361.439 us; speedup vs baseline: 1.9491x; 1.0457x over previous
//
#include <hip/hip_runtime.h>
#include <hip/hip_bf16.h>

// ---------------------------------------------------------------------------
// StateSpaceLite on MI355X.
//   u = x@W_in^T + b_in            (bf16 MFMA GEMM -> d_out, in place)
//   scan over t: driven = tanh(u_t + s@W_state^T + b_state)
//                s' = d*s + (1-d)*driven ; y_t = LN(s')*gamma + beta
// Round-6: same topology as round 4/5 (64 blocks = 16-col slices, all 64
// batch rows via MFMA, W slice in LDS, bf16 state + fp32 LN partials via
// agent-relaxed write-through stores, flag barrier + one acquire/step).
// Change: maximize MLP — ALL global loads of a step (8 Pr float4, 4 u, 32 S
// uint4) are issued up front into registers (launch_bounds(256,1) -> up to
// 512 VGPRs/wave), LN finish + y writes overlap the in-flight S loads, and
// LN stats broadcast via __shfl (producer/consumer same wave) instead of LDS.
// ---------------------------------------------------------------------------

#define B_    64
#define T_    512
#define H_    1024
#define NBLK  64
#define COLS  16
#define KSTEPS 32   // H_/32

typedef __attribute__((ext_vector_type(8))) __bf16 bf16x8;
typedef __attribute__((ext_vector_type(4))) float f32x4;

static __device__ __forceinline__ unsigned f2bf_bits(float f) {
    unsigned u = __float_as_uint(f);
    return (u + 0x7FFFu + ((u >> 16) & 1u)) >> 16;   // RNE, finite inputs
}

static __device__ __forceinline__ float fast_tanh(float x) {
    x = fminf(fmaxf(x, -15.f), 15.f);
    const float e = __expf(2.f * x);                  // finite after clamp
    return 1.f - 2.f * __builtin_amdgcn_rcpf(e + 1.f);
}

// ------------------------------- u GEMM ------------------------------------
// C[m][n] = sum_k X[m][k]*Win[n][k] + bin[n]; M=32768 N=1024 K=512 (verified)
#define BM 128
#define BN 128
#define BKK 32
#define LDT 40

__global__ __launch_bounds__(256)
void u_gemm(const float* __restrict__ X, const float* __restrict__ Win,
            const float* __restrict__ bin, float* __restrict__ U) {
    __shared__ unsigned short Al[BM][LDT];
    __shared__ unsigned short Bl[BN][LDT];
    const int tid = threadIdx.x;
    const int m0 = blockIdx.y * BM;
    const int n0 = blockIdx.x * BN;
    const int l  = tid & 63;
    const int w  = tid >> 6;
    const int wr = (w >> 1) * 64, wc = (w & 1) * 64;
    const int fr = l & 15, fk = (l >> 4) * 8;

    f32x4 acc[4][4];
#pragma unroll
    for (int m = 0; m < 4; ++m)
#pragma unroll
        for (int n = 0; n < 4; ++n) acc[m][n] = f32x4{0.f, 0.f, 0.f, 0.f};

    const int sr = tid >> 1;
    const int sc = (tid & 1) * 16;

    for (int k0 = 0; k0 < 512; k0 += BKK) {
        const float* ap = X   + (size_t)(m0 + sr) * 512 + k0 + sc;
        const float* bp = Win + (size_t)(n0 + sr) * 512 + k0 + sc;
        float a[16], b[16];
#pragma unroll
        for (int j = 0; j < 4; ++j) {
            *(float4*)&a[j * 4] = *(const float4*)(ap + j * 4);
            *(float4*)&b[j * 4] = *(const float4*)(bp + j * 4);
        }
        __syncthreads();
#pragma unroll
        for (int j = 0; j < 16; ++j) {
            Al[sr][sc + j] = (unsigned short)f2bf_bits(a[j]);
            Bl[sr][sc + j] = (unsigned short)f2bf_bits(b[j]);
        }
        __syncthreads();

        bf16x8 af[4], bf[4];
#pragma unroll
        for (int m = 0; m < 4; ++m)
            af[m] = *(const bf16x8*)&Al[wr + m * 16 + fr][fk];
#pragma unroll
        for (int n = 0; n < 4; ++n)
            bf[n] = *(const bf16x8*)&Bl[wc + n * 16 + fr][fk];
#pragma unroll
        for (int m = 0; m < 4; ++m)
#pragma unroll
            for (int n = 0; n < 4; ++n)
                acc[m][n] = __builtin_amdgcn_mfma_f32_16x16x32_bf16(
                    af[m], bf[n], acc[m][n], 0, 0, 0);
    }

#pragma unroll
    for (int m = 0; m < 4; ++m) {
#pragma unroll
        for (int n = 0; n < 4; ++n) {
            const int col = n0 + wc + n * 16 + fr;
            const float bb = bin[col];
#pragma unroll
            for (int r = 0; r < 4; ++r) {
                const int row = m0 + wr + m * 16 + (l >> 4) * 4 + r;
                U[(size_t)row * 1024 + col] = acc[m][n][r] + bb;
            }
        }
    }
}

// ----------------------------- recurrence ----------------------------------
__global__ __launch_bounds__(256, 1)
void rec_mfma(const float* __restrict__ Wst, float* __restrict__ UY,
              const float* __restrict__ b_state, const float* __restrict__ decay,
              const float* __restrict__ gamma, const float* __restrict__ beta,
              unsigned short* __restrict__ S0, unsigned short* __restrict__ S1,
              float2* __restrict__ P0, float2* __restrict__ P1,
              unsigned* __restrict__ flags) {
    __shared__ __align__(16) unsigned short Wl[128][COLS][8];  // [k/8][col][8] bf16

    const int tid  = threadIdx.x;
    const int bid  = blockIdx.x;
    const int h0   = bid * COLS;
    const int wave = tid >> 6;          // 0..3 -> b-tile
    const int lane = tid & 63;
    const int c    = lane & 15;         // local col = A-frag row = C/D col
    const int rgrp = lane >> 4;         // 0..3 (k-chunk / C/D row group)

    // ---- W slice -> LDS (bf16), loaded exactly once ----
    {
        const int col = tid >> 4;       // 0..15
        const int sub = tid & 15;
        const float* wr_ = Wst + (size_t)(h0 + col) * H_ + sub * 64;
#pragma unroll
        for (int i = 0; i < 8; ++i) {
            float4 f0 = *(const float4*)(wr_ + i * 8);
            float4 f1 = *(const float4*)(wr_ + i * 8 + 4);
            unsigned short* dst = &Wl[sub * 8 + i][col][0];
            dst[0] = (unsigned short)f2bf_bits(f0.x);
            dst[1] = (unsigned short)f2bf_bits(f0.y);
            dst[2] = (unsigned short)f2bf_bits(f0.z);
            dst[3] = (unsigned short)f2bf_bits(f0.w);
            dst[4] = (unsigned short)f2bf_bits(f1.x);
            dst[5] = (unsigned short)f2bf_bits(f1.y);
            dst[6] = (unsigned short)f2bf_bits(f1.z);
            dst[7] = (unsigned short)f2bf_bits(f1.w);
        }
    }

    const float d_c  = 1.f / (1.f + __expf(-decay[h0 + c]));
    const float od_c = 1.f - d_c;
    const float bs_c = b_state[h0 + c];
    const float g_c  = gamma[h0 + c];
    const float be_c = beta[h0 + c];

    float sold[4] = {0.f, 0.f, 0.f, 0.f};
    int brow[4];
#pragma unroll
    for (int r = 0; r < 4; ++r) brow[r] = wave * 16 + rgrp * 4 + r;

    // LN-partial ownership: thread handles row prow, quarter pj
    const int prow = tid >> 2, pj = tid & 3;

    // prefetch u for t=0
    float uu[4];
#pragma unroll
    for (int r = 0; r < 4; ++r)
        uu[r] = UY[(size_t)brow[r] * T_ * H_ + h0 + c];

    __syncthreads();

    for (int t = 0; t < T_; ++t) {
        const unsigned short* Sr = (t & 1) ? S1 : S0;
        unsigned short*       Sw = (t & 1) ? S0 : S1;
        float2*               Pw = (t & 1) ? P1 : P0;

        // ==== issue ALL global loads of this step up front (max MLP) ====
        // (1) LN partials of s_t (published at end of step t-1)
        float4 pr[8];
        if (t > 0) {
            const float2* Pr = ((t - 1) & 1) ? P1 : P0;
            const float4* pp = (const float4*)(Pr + prow * NBLK) + pj * 8;
#pragma unroll
            for (int k = 0; k < 8; ++k) pr[k] = pp[k];
        }
        // (2) u for step t+1 (consumed next iteration)
        float uun[4];
        if (t + 1 < T_) {
#pragma unroll
            for (int r = 0; r < 4; ++r)
                uun[r] = UY[((size_t)brow[r] * T_ + (t + 1)) * H_ + h0 + c];
        }
        // (3) full state s_t: 32 x 16B per lane, all in flight
        uint4 sa[KSTEPS];
        const unsigned short* sr_base =
            Sr + (size_t)(wave * 16 + c) * H_ + rgrp * 8;
#pragma unroll
        for (int kk = 0; kk < KSTEPS; ++kk)
            sa[kk] = *(const uint4*)(sr_base + kk * 32);

        // ==== finish LN of s_t + write y_{t-1} (overlaps S loads) ====
        if (t > 0) {
            float s1 = 0.f, s2 = 0.f;
#pragma unroll
            for (int k = 0; k < 8; ++k) {
                s1 += pr[k].x + pr[k].z;
                s2 += pr[k].y + pr[k].w;
            }
            s1 += __shfl_xor(s1, 1); s2 += __shfl_xor(s2, 1);
            s1 += __shfl_xor(s1, 2); s2 += __shfl_xor(s2, 2);
            const float mu_l  = s1 * (1.f / (float)H_);
            const float var_l = s2 * (1.f / (float)H_) - mu_l * mu_l;
            const float rs_l  = rsqrtf(var_l + 1e-5f);
            // stats for row R live in this wave at local lane 4*(R&15)
#pragma unroll
            for (int r = 0; r < 4; ++r) {
                const float mu_r = __shfl(mu_l, rgrp * 16 + r * 4);
                const float rs_r = __shfl(rs_l, rgrp * 16 + r * 4);
                UY[((size_t)brow[r] * T_ + (t - 1)) * H_ + h0 + c] =
                    (sold[r] - mu_r) * rs_r * g_c + be_c;
            }
        }

        // ==== MFMA: acc = s_t @ Wslice^T ====
        f32x4 a0 = {0.f, 0.f, 0.f, 0.f}, a1 = a0, a2 = a0, a3 = a0;
#pragma unroll
        for (int kk = 0; kk < KSTEPS; kk += 4) {
            a0 = __builtin_amdgcn_mfma_f32_16x16x32_bf16(
                __builtin_bit_cast(bf16x8, sa[kk + 0]),
                *(const bf16x8*)(&Wl[(kk + 0) * 4 + rgrp][c][0]), a0, 0, 0, 0);
            a1 = __builtin_amdgcn_mfma_f32_16x16x32_bf16(
                __builtin_bit_cast(bf16x8, sa[kk + 1]),
                *(const bf16x8*)(&Wl[(kk + 1) * 4 + rgrp][c][0]), a1, 0, 0, 0);
            a2 = __builtin_amdgcn_mfma_f32_16x16x32_bf16(
                __builtin_bit_cast(bf16x8, sa[kk + 2]),
                *(const bf16x8*)(&Wl[(kk + 2) * 4 + rgrp][c][0]), a2, 0, 0, 0);
            a3 = __builtin_amdgcn_mfma_f32_16x16x32_bf16(
                __builtin_bit_cast(bf16x8, sa[kk + 3]),
                *(const bf16x8*)(&Wl[(kk + 3) * 4 + rgrp][c][0]), a3, 0, 0, 0);
        }
        const f32x4 acc = (a0 + a1) + (a2 + a3);

        // ==== state update, publish bf16 state + fp32 partials ====
        float p1v[4], p2v[4];
#pragma unroll
        for (int r = 0; r < 4; ++r) {
            const float pre = acc[r] + uu[r] + bs_c;
            const float sn  = d_c * sold[r] + od_c * fast_tanh(pre);
            sold[r] = sn;
            p1v[r] = sn;
            p2v[r] = sn * sn;
            __hip_atomic_store(&Sw[(size_t)brow[r] * H_ + h0 + c],
                               (unsigned short)f2bf_bits(sn),
                               __ATOMIC_RELAXED, __HIP_MEMORY_SCOPE_AGENT);
        }
#pragma unroll
        for (int o = 1; o < 16; o <<= 1) {
#pragma unroll
            for (int r = 0; r < 4; ++r) {
                p1v[r] += __shfl_xor(p1v[r], o);
                p2v[r] += __shfl_xor(p2v[r], o);
            }
        }
        if (c == 0) {
#pragma unroll
            for (int r = 0; r < 4; ++r) {
                const float2 pv = {p1v[r], p2v[r]};
                __hip_atomic_store((unsigned long long*)&Pw[brow[r] * NBLK + bid],
                                   __builtin_bit_cast(unsigned long long, pv),
                                   __ATOMIC_RELAXED, __HIP_MEMORY_SCOPE_AGENT);
            }
        }

#pragma unroll
        for (int r = 0; r < 4; ++r) uu[r] = uun[r];

        // ==== flag barrier; one acquire (buffer_inv) per block per step ====
        __syncthreads();   // compiler drains vmcnt before s_barrier
        if (tid == 0)
            __hip_atomic_store(&flags[bid], (unsigned)(t + 1),
                               __ATOMIC_RELAXED, __HIP_MEMORY_SCOPE_AGENT);
        if (wave == 0) {
            const unsigned tgt = (unsigned)(t + 1);
            for (;;) {
                const unsigned v = __hip_atomic_load(&flags[lane],
                                                     __ATOMIC_RELAXED,
                                                     __HIP_MEMORY_SCOPE_AGENT);
                if (__ballot(v >= tgt) == ~0ull) break;
                __builtin_amdgcn_s_sleep(1);
            }
            __builtin_amdgcn_fence(__ATOMIC_ACQUIRE, "agent");
        }
        __syncthreads();
    }

    // ==== epilogue: y_{T-1} = LN(s_T) from partials published at t=T-1 ====
    {
        const float2* Pr = ((T_ - 1) & 1) ? P1 : P0;
        const float4* pp = (const float4*)(Pr + prow * NBLK) + pj * 8;
        float4 pr[8];
#pragma unroll
        for (int k = 0; k < 8; ++k) pr[k] = pp[k];
        float s1 = 0.f, s2 = 0.f;
#pragma unroll
        for (int k = 0; k < 8; ++k) {
            s1 += pr[k].x + pr[k].z;
            s2 += pr[k].y + pr[k].w;
        }
        s1 += __shfl_xor(s1, 1); s2 += __shfl_xor(s2, 1);
        s1 += __shfl_xor(s1, 2); s2 += __shfl_xor(s2, 2);
        const float mu_l  = s1 * (1.f / (float)H_);
        const float var_l = s2 * (1.f / (float)H_) - mu_l * mu_l;
        const float rs_l  = rsqrtf(var_l + 1e-5f);
#pragma unroll
        for (int r = 0; r < 4; ++r) {
            const float mu_r = __shfl(mu_l, rgrp * 16 + r * 4);
            const float rs_r = __shfl(rs_l, rgrp * 16 + r * 4);
            UY[((size_t)brow[r] * T_ + (T_ - 1)) * H_ + h0 + c] =
                (sold[r] - mu_r) * rs_r * g_c + be_c;
        }
    }
}

// ---------------------------------------------------------------------------
extern "C" void kernel_launch(void* const* d_in, const int* in_sizes, int n_in,
                              void* d_out, int out_size, void* d_ws, size_t ws_size,
                              hipStream_t stream) {
    const float* x   = (const float*)d_in[0];
    const float* Win = (const float*)d_in[1];
    const float* bin = (const float*)d_in[2];
    const float* Wst = (const float*)d_in[3];
    const float* bst = (const float*)d_in[4];
    const float* dec = (const float*)d_in[5];
    const float* lng = (const float*)d_in[6];
    const float* lnb = (const float*)d_in[7];
    float* out = (float*)d_out;

    unsigned char* ws = (unsigned char*)d_ws;
    unsigned*       flags = (unsigned*)ws;                         // 256 B
    unsigned short* S0 = (unsigned short*)(ws + 4096);             // 128 KB
    unsigned short* S1 = (unsigned short*)(ws + 4096 + 131072);    // 128 KB
    float2*         P0 = (float2*)(ws + 4096 + 262144);            // 32 KB
    float2*         P1 = (float2*)(ws + 4096 + 262144 + 32768);    // 32 KB

    // zero flags + S0 (initial state); S1/P0/P1 are written before first read
    hipMemsetAsync(d_ws, 0, 4096 + 131072, stream);
    u_gemm<<<dim3(8, 256), 256, 0, stream>>>(x, Win, bin, out);
    rec_mfma<<<NBLK, 256, 0, stream>>>(Wst, out, bst, dec, lng, lnb,
                                       S0, S1, P0, P1, flags);
}